// Round 4
// baseline (386.584 us; speedup 1.0000x reference)
//
#include <hip/hip_runtime.h>

#define DEVI __device__ __forceinline__

typedef __attribute__((ext_vector_type(8))) short short8;
typedef __attribute__((ext_vector_type(4))) float floatx4;

typedef const __attribute__((address_space(1))) void* gbl_ptr_t;
typedef __attribute__((address_space(3))) void* lds_ptr_t;

// ---------- bf16 helpers (manual, RNE) ----------
DEVI unsigned short f2bf(float f) {
  union { float f; unsigned int u; } v; v.f = f;
  unsigned int r = v.u + 0x7fffu + ((v.u >> 16) & 1u);
  return (unsigned short)(r >> 16);
}

// problem constants
constexpr int Bc = 4, Tc = 2048, Dc = 1024, Hc = 16, DHc = 64;
constexpr int Mrows = Bc * Tc;              // 8192
constexpr long PLANE = (long)Bc * Hc * Tc * DHc;  // 8388608 elems per q/k/v plane

// ---------- cast fp32 -> bf16 (vectorized) ----------
__global__ __launch_bounds__(256) void cast_f32_bf16(const float* __restrict__ in,
                                                     unsigned short* __restrict__ out, int n4) {
  int i = blockIdx.x * 256 + threadIdx.x;
  if (i < n4) {
    float4 v = ((const float4*)in)[i];
    ushort4 o;
    o.x = f2bf(v.x); o.y = f2bf(v.y); o.z = f2bf(v.z); o.w = f2bf(v.w);
    ((ushort4*)out)[i] = o;
  }
}

// ---------- transpose + cast: in fp32 [K,N] -> out bf16 [N,K] ----------
__global__ __launch_bounds__(256) void transpose_cast(const float* __restrict__ in,
                                                      unsigned short* __restrict__ out,
                                                      int K, int N) {
  __shared__ float tile[32][33];
  int bx = blockIdx.x * 32;  // N dim
  int by = blockIdx.y * 32;  // K dim
  int tx = threadIdx.x & 31, ty = threadIdx.x >> 5;  // ty 0..7
#pragma unroll
  for (int i = ty; i < 32; i += 8) tile[i][tx] = in[(long)(by + i) * N + bx + tx];
  __syncthreads();
#pragma unroll
  for (int i = ty; i < 32; i += 8) out[(long)(bx + i) * K + by + tx] = f2bf(tile[tx][i]);
}

// ---------- GEMM: C[M,N] = A[M,K](bf16) @ Bt[N,K](bf16)^T + bias ----------
// m97 structure: global_load_lds width=16 staging into UNPADDED LDS.
// MODE 0: scatter to qkv; q/k planes [bh][T][64], V plane TRANSPOSED [bh][64][T]
//         (so flash can stage V^T tiles with coalesced b128, no b16 scatter).
// MODE 1: plain fp32 [M,N]
template <int MODE>
__global__ __launch_bounds__(256) void gemm_bt(const unsigned short* __restrict__ A,
                                               const unsigned short* __restrict__ Bt,
                                               const float* __restrict__ bias,
                                               void* __restrict__ Cout,
                                               int M, int N, int K) {
  constexpr int BK = 64;
  __shared__ __align__(16) short As[128 * 64];
  __shared__ __align__(16) short Bs[128 * 64];

  const int tid = threadIdx.x;
  const int wave = tid >> 6;
  const int lane = tid & 63;
  const int l16 = lane & 15;
  const int quad = lane >> 4;
  const int wm = (wave >> 1) * 64;
  const int wn = (wave & 1) * 64;
  const int rsub = lane >> 3;        // 0..7 row within 8-row chunk
  const int csub = (lane & 7) * 8;   // col (bf16 elems) within 64-col row

  const long row0 = (long)blockIdx.y * 128;
  const long col0 = (long)blockIdx.x * 128;

  floatx4 acc[4][4];
#pragma unroll
  for (int i = 0; i < 4; i++)
#pragma unroll
    for (int j = 0; j < 4; j++) acc[i][j] = (floatx4){0.f, 0.f, 0.f, 0.f};

  for (int k0 = 0; k0 < K; k0 += BK) {
#pragma unroll
    for (int c = 0; c < 4; c++) {
      int rb = (c * 4 + wave) * 8;   // 8-row chunk base, wave-uniform
      const unsigned short* sA = &A[(row0 + rb + rsub) * (long)K + k0 + csub];
      __builtin_amdgcn_global_load_lds((gbl_ptr_t)sA, (lds_ptr_t)&As[rb * 64], 16, 0, 0);
      const unsigned short* sB = &Bt[(col0 + rb + rsub) * (long)K + k0 + csub];
      __builtin_amdgcn_global_load_lds((gbl_ptr_t)sB, (lds_ptr_t)&Bs[rb * 64], 16, 0, 0);
    }
    __syncthreads();   // drains vmcnt -> tiles resident
#pragma unroll
    for (int kk = 0; kk < BK; kk += 32) {
      short8 af[4], bfr[4];
#pragma unroll
      for (int mt = 0; mt < 4; mt++)
        af[mt] = *(const short8*)&As[(wm + mt * 16 + l16) * 64 + kk + quad * 8];
#pragma unroll
      for (int nt = 0; nt < 4; nt++)
        bfr[nt] = *(const short8*)&Bs[(wn + nt * 16 + l16) * 64 + kk + quad * 8];
#pragma unroll
      for (int mt = 0; mt < 4; mt++)
#pragma unroll
        for (int nt = 0; nt < 4; nt++)
          acc[mt][nt] = __builtin_amdgcn_mfma_f32_16x16x32_bf16(af[mt], bfr[nt], acc[mt][nt], 0, 0, 0);
    }
    __syncthreads();
  }

#pragma unroll
  for (int mt = 0; mt < 4; mt++)
#pragma unroll
    for (int nt = 0; nt < 4; nt++)
#pragma unroll
      for (int r = 0; r < 4; r++) {
        long row = row0 + wm + mt * 16 + quad * 4 + r;
        long col = col0 + wn + nt * 16 + l16;
        float v = acc[mt][nt][r] + bias[col];
        if (MODE == 0) {
          int which = (int)(col >> 10);
          int hc = (int)col & 1023;
          int h = hc >> 6, d = hc & 63;
          int b = (int)(row >> 11), t = (int)row & 2047;
          long bh = b * Hc + h;
          if (which == 2) {
            // V plane transposed: [bh][d][T]
            ((unsigned short*)Cout)[2 * PLANE + bh * (64L * Tc) + (long)d * Tc + t] = f2bf(v);
          } else {
            ((unsigned short*)Cout)[(long)which * PLANE + ((bh * Tc + t) << 6) + d] = f2bf(v);
          }
        } else {
          ((float*)Cout)[row * N + col] = v;
        }
      }
}

// ---------- flash attention v4 ----------
// q/k planes [bh][T][64]; V plane pre-transposed [bh][64][T].
// S^T = mfma(A=K-frag, B=Q-frag): C-layout gives lane (l16=q, quad*4+r=key) ->
// P^T store = 4 packed ds_write_b64 (no b16 scatter); PV reads P as A-operand
// contiguously. l is one register/lane (row q=l16), reduced once at the end.
// Register prefetch of K/V^T; 2 barriers/tile; grid (bh, pair) so all 16
// q-blocks of a bh land on one XCD (linear_id % 8 == bh % 8).
__global__ __launch_bounds__(256) void flash_attn(const unsigned short* __restrict__ qkv,
                                                  unsigned short* __restrict__ attn_out) {
  constexpr int PD = 80;  // 160 B row stride: 16B-aligned, 4-way bank alias on b128 frags
  __shared__ __align__(16) short Ks[64 * PD];
  __shared__ __align__(16) short Vts[64 * PD];    // [d][key]
  __shared__ __align__(16) short Ps[4 * 16 * PD]; // per-wave P^T as [q][key]

  const int tid = threadIdx.x;
  const int wave = tid >> 6;
  const int lane = tid & 63;
  const int l16 = lane & 15;
  const int quad = lane >> 4;

  const int bh = blockIdx.x;          // b*16 + h
  const unsigned short* Qg = qkv + (long)bh * Tc * DHc;
  const unsigned short* Kg = qkv + PLANE + (long)bh * Tc * DHc;
  const unsigned short* VgT = qkv + 2 * PLANE + (long)bh * (64L * Tc);  // [d][T]
  const int b = bh >> 4, h = bh & 15;

  constexpr float CEXP = 0.125f * 1.44269504f;  // 1/sqrt(64) folded into exp2
  short* Pw = &Ps[wave * 16 * PD];

  const int kr = tid >> 3;            // 0..31
  const int kc = (tid & 7) * 8;

#pragma unroll 1
  for (int pass = 0; pass < 2; pass++) {
    const int qx = (pass == 0) ? (int)blockIdx.y : (31 - (int)blockIdx.y);
    const int q0 = qx * 64 + wave * 16;  // wave's first q row

    // Q fragment (B-operand for S^T; same per-lane layout as A-frag)
    short8 qf[2];
#pragma unroll
    for (int kk = 0; kk < 2; kk++)
      qf[kk] = *(const short8*)&Qg[(long)(q0 + l16) * 64 + kk * 32 + quad * 8];

    floatx4 oacc[4];
#pragma unroll
    for (int j = 0; j < 4; j++) oacc[j] = (floatx4){0.f, 0.f, 0.f, 0.f};
    float lp = 0.f;  // row-sum partial for q = q0 + l16 (this lane's 16 keys/tile)

    const int ntiles = qx + 1;

    // prologue: prefetch tile 0
    uint4 Kreg[2], Vreg[2];
    Kreg[0] = *(const uint4*)&Kg[(long)kr * 64 + kc];
    Kreg[1] = *(const uint4*)&Kg[(long)(32 + kr) * 64 + kc];
    Vreg[0] = *(const uint4*)&VgT[(long)kr * Tc + kc];
    Vreg[1] = *(const uint4*)&VgT[(long)(32 + kr) * Tc + kc];

#pragma unroll 1
    for (int kt = 0; kt < ntiles; kt++) {
      __syncthreads();  // all waves done reading LDS from previous tile
      *(uint4*)&Ks[kr * PD + kc] = Kreg[0];
      *(uint4*)&Ks[(32 + kr) * PD + kc] = Kreg[1];
      *(uint4*)&Vts[kr * PD + kc] = Vreg[0];
      *(uint4*)&Vts[(32 + kr) * PD + kc] = Vreg[1];
      __syncthreads();  // staging visible
      if (kt + 1 < ntiles) {
        long koff = (long)(kt + 1) * 64;
        Kreg[0] = *(const uint4*)&Kg[(koff + kr) * 64 + kc];
        Kreg[1] = *(const uint4*)&Kg[(koff + 32 + kr) * 64 + kc];
        Vreg[0] = *(const uint4*)&VgT[(long)kr * Tc + koff + kc];
        Vreg[1] = *(const uint4*)&VgT[(long)(32 + kr) * Tc + koff + kc];
      }

      // S^T[key][q] = K @ Q^T : sacc[nt] covers keys nt*16..+16, q = q0..q0+15
      floatx4 sacc[4];
#pragma unroll
      for (int j = 0; j < 4; j++) sacc[j] = (floatx4){0.f, 0.f, 0.f, 0.f};
#pragma unroll
      for (int kk = 0; kk < 2; kk++) {
        short8 kf[4];
#pragma unroll
        for (int nt = 0; nt < 4; nt++)
          kf[nt] = *(const short8*)&Ks[(nt * 16 + l16) * PD + kk * 32 + quad * 8];
#pragma unroll
        for (int nt = 0; nt < 4; nt++)
          sacc[nt] = __builtin_amdgcn_mfma_f32_16x16x32_bf16(kf[nt], qf[kk], sacc[nt], 0, 0, 0);
      }

      // causal mask on diagonal tile: key index = kt*64+nt*16+quad*4+r, q = q0+l16
      if (kt == qx) {
        int qi = q0 + l16;
#pragma unroll
        for (int nt = 0; nt < 4; nt++) {
          int kbase = kt * 64 + nt * 16 + quad * 4;
#pragma unroll
          for (int r = 0; r < 4; r++)
            if (kbase + r > qi) sacc[nt][r] = -3.0e38f;
        }
      }

      // p = exp(s/8); per-lane row-sum partial (no cross-lane)
#pragma unroll
      for (int nt = 0; nt < 4; nt++)
#pragma unroll
        for (int r = 0; r < 4; r++) sacc[nt][r] = exp2f(sacc[nt][r] * CEXP);
#pragma unroll
      for (int nt = 0; nt < 4; nt++)
        lp += (sacc[nt][0] + sacc[nt][1]) + (sacc[nt][2] + sacc[nt][3]);

      // P^T -> Pw[q=l16][key]: 4 consecutive keys per lane -> packed b64 stores
#pragma unroll
      for (int nt = 0; nt < 4; nt++) {
        unsigned int u0 = (unsigned int)f2bf(sacc[nt][0]) | ((unsigned int)f2bf(sacc[nt][1]) << 16);
        unsigned int u1 = (unsigned int)f2bf(sacc[nt][2]) | ((unsigned int)f2bf(sacc[nt][3]) << 16);
        uint2 u = {u0, u1};
        *(uint2*)&Pw[l16 * PD + nt * 16 + quad * 4] = u;
      }

      // O += P @ V : A=P[q][key] from Pw, B=V^T[d][key] from Vts
#pragma unroll
      for (int kk = 0; kk < 2; kk++) {
        short8 pf = *(const short8*)&Pw[l16 * PD + kk * 32 + quad * 8];
        short8 vf[4];
#pragma unroll
        for (int dt = 0; dt < 4; dt++)
          vf[dt] = *(const short8*)&Vts[(dt * 16 + l16) * PD + kk * 32 + quad * 8];
#pragma unroll
        for (int dt = 0; dt < 4; dt++)
          oacc[dt] = __builtin_amdgcn_mfma_f32_16x16x32_bf16(pf, vf[dt], oacc[dt], 0, 0, 0);
      }
    }

    // epilogue: reduce l across quads (row q = l16), redistribute to C-layout rows
    float lv = lp + __shfl_xor(lp, 16);
    lv += __shfl_xor(lv, 32);           // all lanes: full row-sum for q = l16
#pragma unroll
    for (int r = 0; r < 4; r++) {
      float lr = __shfl(lv, quad * 4 + r);  // l for this lane's C-row q = quad*4+r
      float inv = 1.0f / lr;
      int t = q0 + quad * 4 + r;
#pragma unroll
      for (int dt = 0; dt < 4; dt++) {
        int d = dt * 16 + l16;
        attn_out[(((long)(b * Tc + t) * Hc + h) << 6) + d] = f2bf(oacc[dt][r] * inv);
      }
    }
  }
}

// ---------- launch ----------
extern "C" void kernel_launch(void* const* d_in, const int* in_sizes, int n_in,
                              void* d_out, int out_size, void* d_ws, size_t ws_size,
                              hipStream_t stream) {
  const float* x = (const float*)d_in[0];
  const float* Wqkv = (const float*)d_in[1];
  const float* bqkv = (const float*)d_in[2];
  const float* Wout = (const float*)d_in[3];
  const float* bout = (const float*)d_in[4];

  char* ws = (char*)d_ws;
  unsigned short* x_bf   = (unsigned short*)ws;                       // 16 MB
  unsigned short* wqkv_t = (unsigned short*)(ws + 16777216);          // 6 MB
  unsigned short* wout_t = (unsigned short*)(ws + 16777216 + 6291456);// 2 MB
  unsigned short* qkv    = (unsigned short*)(ws + 25165824);          // 48 MB
  unsigned short* attn   = x_bf;  // reuse: x_bf dead after GEMM1

  // 1. casts / transposes
  cast_f32_bf16<<<dim3(Mrows * Dc / 4 / 256), dim3(256), 0, stream>>>(x, x_bf, Mrows * Dc / 4);
  transpose_cast<<<dim3(3 * Dc / 32, Dc / 32), dim3(256), 0, stream>>>(Wqkv, wqkv_t, Dc, 3 * Dc);
  transpose_cast<<<dim3(Dc / 32, Dc / 32), dim3(256), 0, stream>>>(Wout, wout_t, Dc, Dc);

  // 2. QKV projection (V plane written transposed)
  gemm_bt<0><<<dim3(3 * Dc / 128, Mrows / 128), dim3(256), 0, stream>>>(
      x_bf, wqkv_t, bqkv, qkv, Mrows, 3 * Dc, Dc);

  // 3. flash attention; grid (bh, pair): all q-blocks of a bh on one XCD
  flash_attn<<<dim3(Bc * Hc, 16), dim3(256), 0, stream>>>(qkv, attn);

  // 4. output projection (fp32 out + bias)
  gemm_bt<1><<<dim3(Dc / 128, Mrows / 128), dim3(256), 0, stream>>>(
      attn, wout_t, bout, d_out, Mrows, Dc, Dc);
}

// Round 5
// 335.096 us; speedup vs baseline: 1.1537x; 1.1537x over previous
//
#include <hip/hip_runtime.h>

#define DEVI __device__ __forceinline__

typedef __attribute__((ext_vector_type(8))) short short8;
typedef __attribute__((ext_vector_type(4))) float floatx4;

typedef const __attribute__((address_space(1))) void* gbl_ptr_t;
typedef __attribute__((address_space(3))) void* lds_ptr_t;

// ---------- bf16 helpers (manual, RNE) ----------
DEVI unsigned short f2bf(float f) {
  union { float f; unsigned int u; } v; v.f = f;
  unsigned int r = v.u + 0x7fffu + ((v.u >> 16) & 1u);
  return (unsigned short)(r >> 16);
}

// lane <-> lane^1 exchange on the VALU pipe (DPP quad_perm [1,0,3,2])
DEVI unsigned dppx1(unsigned x) {
  return (unsigned)__builtin_amdgcn_update_dpp(0, (int)x, 0xB1, 0xF, 0xF, true);
}

// problem constants
constexpr int Bc = 4, Tc = 2048, Dc = 1024, Hc = 16, DHc = 64;
constexpr int Mrows = Bc * Tc;              // 8192
constexpr long PLANE = (long)Bc * Hc * Tc * DHc;  // 8388608 elems per q/k/v plane

// ---------- cast fp32 -> bf16 (vectorized) ----------
__global__ __launch_bounds__(256) void cast_f32_bf16(const float* __restrict__ in,
                                                     unsigned short* __restrict__ out, int n4) {
  int i = blockIdx.x * 256 + threadIdx.x;
  if (i < n4) {
    float4 v = ((const float4*)in)[i];
    ushort4 o;
    o.x = f2bf(v.x); o.y = f2bf(v.y); o.z = f2bf(v.z); o.w = f2bf(v.w);
    ((ushort4*)out)[i] = o;
  }
}

// ---------- transpose + cast: in fp32 [K,N] -> out bf16 [N,K] ----------
__global__ __launch_bounds__(256) void transpose_cast(const float* __restrict__ in,
                                                      unsigned short* __restrict__ out,
                                                      int K, int N) {
  __shared__ float tile[32][33];
  int bx = blockIdx.x * 32;  // N dim
  int by = blockIdx.y * 32;  // K dim
  int tx = threadIdx.x & 31, ty = threadIdx.x >> 5;  // ty 0..7
#pragma unroll
  for (int i = ty; i < 32; i += 8) tile[i][tx] = in[(long)(by + i) * N + bx + tx];
  __syncthreads();
#pragma unroll
  for (int i = ty; i < 32; i += 8) out[(long)(bx + i) * K + by + tx] = f2bf(tile[tx][i]);
}

// ---------- GEMM: C[M,N] = A[M,K](bf16) @ Bt[N,K](bf16)^T + bias ----------
// m97 structure: global_load_lds width=16 staging into UNPADDED LDS.
// MODE 0: scatter to qkv bf16 [3][B*H][T][64];  MODE 1: plain fp32 [M,N]
template <int MODE>
__global__ __launch_bounds__(256) void gemm_bt(const unsigned short* __restrict__ A,
                                               const unsigned short* __restrict__ Bt,
                                               const float* __restrict__ bias,
                                               void* __restrict__ Cout,
                                               int M, int N, int K) {
  constexpr int BK = 64;
  __shared__ __align__(16) short As[128 * 64];
  __shared__ __align__(16) short Bs[128 * 64];

  const int tid = threadIdx.x;
  const int wave = tid >> 6;
  const int lane = tid & 63;
  const int l16 = lane & 15;
  const int quad = lane >> 4;
  const int wm = (wave >> 1) * 64;
  const int wn = (wave & 1) * 64;
  const int rsub = lane >> 3;        // 0..7 row within 8-row chunk
  const int csub = (lane & 7) * 8;   // col (bf16 elems) within 64-col row

  const long row0 = (long)blockIdx.y * 128;
  const long col0 = (long)blockIdx.x * 128;

  floatx4 acc[4][4];
#pragma unroll
  for (int i = 0; i < 4; i++)
#pragma unroll
    for (int j = 0; j < 4; j++) acc[i][j] = (floatx4){0.f, 0.f, 0.f, 0.f};

  for (int k0 = 0; k0 < K; k0 += BK) {
#pragma unroll
    for (int c = 0; c < 4; c++) {
      int rb = (c * 4 + wave) * 8;   // 8-row chunk base, wave-uniform
      const unsigned short* sA = &A[(row0 + rb + rsub) * (long)K + k0 + csub];
      __builtin_amdgcn_global_load_lds((gbl_ptr_t)sA, (lds_ptr_t)&As[rb * 64], 16, 0, 0);
      const unsigned short* sB = &Bt[(col0 + rb + rsub) * (long)K + k0 + csub];
      __builtin_amdgcn_global_load_lds((gbl_ptr_t)sB, (lds_ptr_t)&Bs[rb * 64], 16, 0, 0);
    }
    __syncthreads();   // drains vmcnt -> tiles resident
#pragma unroll
    for (int kk = 0; kk < BK; kk += 32) {
      short8 af[4], bfr[4];
#pragma unroll
      for (int mt = 0; mt < 4; mt++)
        af[mt] = *(const short8*)&As[(wm + mt * 16 + l16) * 64 + kk + quad * 8];
#pragma unroll
      for (int nt = 0; nt < 4; nt++)
        bfr[nt] = *(const short8*)&Bs[(wn + nt * 16 + l16) * 64 + kk + quad * 8];
#pragma unroll
      for (int mt = 0; mt < 4; mt++)
#pragma unroll
        for (int nt = 0; nt < 4; nt++)
          acc[mt][nt] = __builtin_amdgcn_mfma_f32_16x16x32_bf16(af[mt], bfr[nt], acc[mt][nt], 0, 0, 0);
    }
    __syncthreads();
  }

#pragma unroll
  for (int mt = 0; mt < 4; mt++)
#pragma unroll
    for (int nt = 0; nt < 4; nt++)
#pragma unroll
      for (int r = 0; r < 4; r++) {
        long row = row0 + wm + mt * 16 + quad * 4 + r;
        long col = col0 + wn + nt * 16 + l16;
        float v = acc[mt][nt][r] + bias[col];
        if (MODE == 0) {
          int which = (int)(col >> 10);
          int hc = (int)col & 1023;
          int h = hc >> 6, d = hc & 63;
          int b = (int)(row >> 11), t = (int)row & 2047;
          ((unsigned short*)Cout)[(long)which * PLANE +
                                  (((long)(b * Hc + h) * Tc + t) << 6) + d] = f2bf(v);
        } else {
          ((float*)Cout)[row * N + col] = v;
        }
      }
}

// ---------- flash attention v5 ----------
// = round-3 structure (126 us measured) + two LDS-write reductions:
//  (1) S^T = mfma(A=K-frag, B=Q-frag): C-layout holds P^T with 4 consecutive
//      keys per lane -> P store = 4 packed ds_write_b64 (was 16 ds_write_b16).
//      l becomes one register/lane (row q = l16), reduced once in epilogue.
//  (2) V^T LDS build via DPP lane-pairing: lanes 2m/2m+1 swap half-rows on the
//      VALU pipe, then 8 conflict-free ds_write_b32 (was 16 ds_write_b16).
// PD=72 (2-way bank alias = free); grid (16, 64); V plane normal layout.
__global__ __launch_bounds__(256) void flash_attn(const unsigned short* __restrict__ qkv,
                                                  unsigned short* __restrict__ attn_out) {
  constexpr int PD = 72;
  __shared__ __align__(16) short Ks[64 * PD];
  __shared__ __align__(16) short Vts[64 * PD];    // transposed: [d][key]
  __shared__ __align__(16) short Ps[4 * 16 * PD]; // per-wave P^T as [q][key]

  const int tid = threadIdx.x;
  const int wave = tid >> 6;
  const int lane = tid & 63;
  const int l16 = lane & 15;
  const int quad = lane >> 4;

  const int bh = blockIdx.y;          // b*16 + h
  const long base = (long)bh * Tc * DHc;
  const unsigned short* Qg = qkv + base;
  const unsigned short* Kg = qkv + PLANE + base;
  const unsigned short* Vg = qkv + 2 * PLANE + base;
  const int b = bh >> 4, h = bh & 15;

  constexpr float CEXP = 0.125f * 1.44269504f;  // 1/sqrt(64) folded into exp2
  short* Pw = &Ps[wave * 16 * PD];

  const int kr = tid >> 3;            // 0..31
  const int kc = (tid & 7) * 8;

#pragma unroll 1
  for (int pass = 0; pass < 2; pass++) {
    const int qx = (pass == 0) ? (int)blockIdx.x : (31 - (int)blockIdx.x);
    const int q0 = qx * 64 + wave * 16;  // wave's first q row

    // Q fragment (B-operand for S^T; A/B frags share the same per-lane layout)
    short8 qf[2];
#pragma unroll
    for (int kk = 0; kk < 2; kk++)
      qf[kk] = *(const short8*)&Qg[(long)(q0 + l16) * 64 + kk * 32 + quad * 8];

    floatx4 oacc[4];
#pragma unroll
    for (int j = 0; j < 4; j++) oacc[j] = (floatx4){0.f, 0.f, 0.f, 0.f};
    float lp = 0.f;  // row-sum partial for q = q0 + l16 (this lane's 16 keys/tile)

    const int ntiles = qx + 1;

    // prologue: prefetch tile 0 into regs
    uint4 Kreg[2], Vreg[2];
    Kreg[0] = *(const uint4*)&Kg[(long)kr * 64 + kc];
    Kreg[1] = *(const uint4*)&Kg[(long)(32 + kr) * 64 + kc];
    Vreg[0] = *(const uint4*)&Vg[(long)lane * 64 + wave * 8];
    Vreg[1] = *(const uint4*)&Vg[(long)lane * 64 + (wave + 4) * 8];

#pragma unroll 1
    for (int kt = 0; kt < ntiles; kt++) {
      __syncthreads();  // all waves done reading LDS from previous tile
      // commit K
      *(uint4*)&Ks[kr * PD + kc] = Kreg[0];
      *(uint4*)&Ks[(32 + kr) * PD + kc] = Kreg[1];
      // commit V transposed: DPP pair-exchange, then packed b32 writes.
      // lane holds V[key=kt*64+lane][dbase..dbase+8); pair (2m, 2m+1) swaps
      // half-rows so each lane owns a key-PAIR for 4 d's -> Vts[d][2m..2m+1].
      {
        const int odd = lane & 1;
        const int kb = lane & ~1;  // key pair base within tile
#pragma unroll
        for (int c = 0; c < 2; c++) {
          const int dbase = (wave + 4 * c) * 8;
          uint4 v = Vreg[c];
          unsigned mlo = odd ? v.z : v.x, mhi = odd ? v.w : v.y;   // kept half
          unsigned glo = odd ? v.x : v.z, ghi = odd ? v.y : v.w;   // given half
          unsigned rlo = dppx1(glo), rhi = dppx1(ghi);             // received
          unsigned ms[4] = {mlo & 0xffffu, mlo >> 16, mhi & 0xffffu, mhi >> 16};
          unsigned gs[4] = {rlo & 0xffffu, rlo >> 16, rhi & 0xffffu, rhi >> 16};
          const int dlo = dbase + (odd ? 4 : 0);
#pragma unroll
          for (int j = 0; j < 4; j++) {
            unsigned lo = odd ? gs[j] : ms[j];   // V[2m][d]
            unsigned hi = odd ? ms[j] : gs[j];   // V[2m+1][d]
            *(unsigned*)&Vts[(dlo + j) * PD + kb] = lo | (hi << 16);
          }
        }
      }
      __syncthreads();  // staging visible
      // prefetch next tile (latency hidden behind compute)
      if (kt + 1 < ntiles) {
        long koff = (long)(kt + 1) * 64;
        Kreg[0] = *(const uint4*)&Kg[(koff + kr) * 64 + kc];
        Kreg[1] = *(const uint4*)&Kg[(koff + 32 + kr) * 64 + kc];
        Vreg[0] = *(const uint4*)&Vg[(koff + lane) * 64 + wave * 8];
        Vreg[1] = *(const uint4*)&Vg[(koff + lane) * 64 + (wave + 4) * 8];
      }

      // S^T[key][q]: sacc[nt] = keys nt*16+quad*4+r, q = q0+l16
      floatx4 sacc[4];
#pragma unroll
      for (int j = 0; j < 4; j++) sacc[j] = (floatx4){0.f, 0.f, 0.f, 0.f};
#pragma unroll
      for (int kk = 0; kk < 2; kk++) {
        short8 kf[4];
#pragma unroll
        for (int nt = 0; nt < 4; nt++)
          kf[nt] = *(const short8*)&Ks[(nt * 16 + l16) * PD + kk * 32 + quad * 8];
#pragma unroll
        for (int nt = 0; nt < 4; nt++)
          sacc[nt] = __builtin_amdgcn_mfma_f32_16x16x32_bf16(kf[nt], qf[kk], sacc[nt], 0, 0, 0);
      }

      // causal mask on diagonal tile: key = kt*64+nt*16+quad*4+r, q = q0+l16
      if (kt == qx) {
        int qi = q0 + l16;
#pragma unroll
        for (int nt = 0; nt < 4; nt++) {
          int kbase = kt * 64 + nt * 16 + quad * 4;
#pragma unroll
          for (int r = 0; r < 4; r++)
            if (kbase + r > qi) sacc[nt][r] = -3.0e38f;
        }
      }

      // p = exp(s/8); per-lane row-sum partial (no cross-lane work here)
#pragma unroll
      for (int nt = 0; nt < 4; nt++)
#pragma unroll
        for (int r = 0; r < 4; r++) sacc[nt][r] = exp2f(sacc[nt][r] * CEXP);
#pragma unroll
      for (int nt = 0; nt < 4; nt++)
        lp += (sacc[nt][0] + sacc[nt][1]) + (sacc[nt][2] + sacc[nt][3]);

      // P^T -> Pw[q=l16][key]: 4 consecutive keys per lane -> packed b64
#pragma unroll
      for (int nt = 0; nt < 4; nt++) {
        unsigned u0 = (unsigned)f2bf(sacc[nt][0]) | ((unsigned)f2bf(sacc[nt][1]) << 16);
        unsigned u1 = (unsigned)f2bf(sacc[nt][2]) | ((unsigned)f2bf(sacc[nt][3]) << 16);
        uint2 u = {u0, u1};
        *(uint2*)&Pw[l16 * PD + nt * 16 + quad * 4] = u;
      }

      // O += P @ V : A = P[q][key] (wave-private), B = V^T[d][key]
#pragma unroll
      for (int kk = 0; kk < 2; kk++) {
        short8 pf = *(const short8*)&Pw[l16 * PD + kk * 32 + quad * 8];
        short8 vf[4];
#pragma unroll
        for (int dt = 0; dt < 4; dt++)
          vf[dt] = *(const short8*)&Vts[(dt * 16 + l16) * PD + kk * 32 + quad * 8];
#pragma unroll
        for (int dt = 0; dt < 4; dt++)
          oacc[dt] = __builtin_amdgcn_mfma_f32_16x16x32_bf16(pf, vf[dt], oacc[dt], 0, 0, 0);
      }
    }

    // epilogue: reduce l across quads (row q = l16), redistribute to C-rows
    float lv = lp + __shfl_xor(lp, 16);
    lv += __shfl_xor(lv, 32);             // all lanes: full row-sum for q = l16
#pragma unroll
    for (int r = 0; r < 4; r++) {
      float lr = __shfl(lv, quad * 4 + r); // l for this lane's C-row q = quad*4+r
      float inv = 1.0f / lr;
      int t = q0 + quad * 4 + r;
#pragma unroll
      for (int dt = 0; dt < 4; dt++) {
        int d = dt * 16 + l16;
        attn_out[(((long)(b * Tc + t) * Hc + h) << 6) + d] = f2bf(oacc[dt][r] * inv);
      }
    }
  }
}

// ---------- launch ----------
extern "C" void kernel_launch(void* const* d_in, const int* in_sizes, int n_in,
                              void* d_out, int out_size, void* d_ws, size_t ws_size,
                              hipStream_t stream) {
  const float* x = (const float*)d_in[0];
  const float* Wqkv = (const float*)d_in[1];
  const float* bqkv = (const float*)d_in[2];
  const float* Wout = (const float*)d_in[3];
  const float* bout = (const float*)d_in[4];

  char* ws = (char*)d_ws;
  unsigned short* x_bf   = (unsigned short*)ws;                       // 16 MB
  unsigned short* wqkv_t = (unsigned short*)(ws + 16777216);          // 6 MB
  unsigned short* wout_t = (unsigned short*)(ws + 16777216 + 6291456);// 2 MB
  unsigned short* qkv    = (unsigned short*)(ws + 25165824);          // 48 MB
  unsigned short* attn   = x_bf;  // reuse: x_bf dead after GEMM1

  // 1. casts / transposes
  cast_f32_bf16<<<dim3(Mrows * Dc / 4 / 256), dim3(256), 0, stream>>>(x, x_bf, Mrows * Dc / 4);
  transpose_cast<<<dim3(3 * Dc / 32, Dc / 32), dim3(256), 0, stream>>>(Wqkv, wqkv_t, Dc, 3 * Dc);
  transpose_cast<<<dim3(Dc / 32, Dc / 32), dim3(256), 0, stream>>>(Wout, wout_t, Dc, Dc);

  // 2. QKV projection
  gemm_bt<0><<<dim3(3 * Dc / 128, Mrows / 128), dim3(256), 0, stream>>>(
      x_bf, wqkv_t, bqkv, qkv, Mrows, 3 * Dc, Dc);

  // 3. flash attention (paired q-tiles, uniform 33 key-tiles per block)
  flash_attn<<<dim3(16, Bc * Hc), dim3(256), 0, stream>>>(qkv, attn);

  // 4. output projection (fp32 out + bias)
  gemm_bt<1><<<dim3(Dc / 128, Mrows / 128), dim3(256), 0, stream>>>(
      attn, wout_t, bout, d_out, Mrows, Dc, Dc);
}

// Round 6
// 324.836 us; speedup vs baseline: 1.1901x; 1.0316x over previous
//
#include <hip/hip_runtime.h>

#define DEVI __device__ __forceinline__

typedef __attribute__((ext_vector_type(8))) short short8;
typedef __attribute__((ext_vector_type(4))) short short4_t;
typedef __attribute__((ext_vector_type(4))) float floatx4;

typedef const __attribute__((address_space(1))) void* gbl_ptr_t;
typedef __attribute__((address_space(3))) void* lds_ptr_t;

#if __has_builtin(__builtin_amdgcn_mfma_f32_16x16x16bf16_1k)
#define HAVE_MFMA16 1
#else
#define HAVE_MFMA16 0
#endif

// ---------- bf16 helpers (manual, RNE) ----------
DEVI unsigned short f2bf(float f) {
  union { float f; unsigned int u; } v; v.f = f;
  unsigned int r = v.u + 0x7fffu + ((v.u >> 16) & 1u);
  return (unsigned short)(r >> 16);
}

// problem constants
constexpr int Bc = 4, Tc = 2048, Dc = 1024, Hc = 16, DHc = 64;
constexpr int Mrows = Bc * Tc;              // 8192
constexpr long PLANE = (long)Bc * Hc * Tc * DHc;  // 8388608 elems per q/k/v plane

// ---------- cast fp32 -> bf16 (vectorized) ----------
__global__ __launch_bounds__(256) void cast_f32_bf16(const float* __restrict__ in,
                                                     unsigned short* __restrict__ out, int n4) {
  int i = blockIdx.x * 256 + threadIdx.x;
  if (i < n4) {
    float4 v = ((const float4*)in)[i];
    ushort4 o;
    o.x = f2bf(v.x); o.y = f2bf(v.y); o.z = f2bf(v.z); o.w = f2bf(v.w);
    ((ushort4*)out)[i] = o;
  }
}

// ---------- transpose + cast: in fp32 [K,N] -> out bf16 [N,K] ----------
__global__ __launch_bounds__(256) void transpose_cast(const float* __restrict__ in,
                                                      unsigned short* __restrict__ out,
                                                      int K, int N) {
  __shared__ float tile[32][33];
  int bx = blockIdx.x * 32;  // N dim
  int by = blockIdx.y * 32;  // K dim
  int tx = threadIdx.x & 31, ty = threadIdx.x >> 5;  // ty 0..7
#pragma unroll
  for (int i = ty; i < 32; i += 8) tile[i][tx] = in[(long)(by + i) * N + bx + tx];
  __syncthreads();
#pragma unroll
  for (int i = ty; i < 32; i += 8) out[(long)(bx + i) * K + by + tx] = f2bf(tile[tx][i]);
}

// ---------- GEMM: C[M,N] = A[M,K](bf16) @ Bt[N,K](bf16)^T + bias ----------
// m97 structure: global_load_lds width=16 staging into UNPADDED LDS.
// MODE 0: scatter to qkv bf16 [3][B*H][T][64];  MODE 1: plain fp32 [M,N]
template <int MODE>
__global__ __launch_bounds__(256) void gemm_bt(const unsigned short* __restrict__ A,
                                               const unsigned short* __restrict__ Bt,
                                               const float* __restrict__ bias,
                                               void* __restrict__ Cout,
                                               int M, int N, int K) {
  constexpr int BK = 64;
  __shared__ __align__(16) short As[128 * 64];
  __shared__ __align__(16) short Bs[128 * 64];

  const int tid = threadIdx.x;
  const int wave = tid >> 6;
  const int lane = tid & 63;
  const int l16 = lane & 15;
  const int quad = lane >> 4;
  const int wm = (wave >> 1) * 64;
  const int wn = (wave & 1) * 64;
  const int rsub = lane >> 3;        // 0..7 row within 8-row chunk
  const int csub = (lane & 7) * 8;   // col (bf16 elems) within 64-col row

  const long row0 = (long)blockIdx.y * 128;
  const long col0 = (long)blockIdx.x * 128;

  floatx4 acc[4][4];
#pragma unroll
  for (int i = 0; i < 4; i++)
#pragma unroll
    for (int j = 0; j < 4; j++) acc[i][j] = (floatx4){0.f, 0.f, 0.f, 0.f};

  for (int k0 = 0; k0 < K; k0 += BK) {
#pragma unroll
    for (int c = 0; c < 4; c++) {
      int rb = (c * 4 + wave) * 8;   // 8-row chunk base, wave-uniform
      const unsigned short* sA = &A[(row0 + rb + rsub) * (long)K + k0 + csub];
      __builtin_amdgcn_global_load_lds((gbl_ptr_t)sA, (lds_ptr_t)&As[rb * 64], 16, 0, 0);
      const unsigned short* sB = &Bt[(col0 + rb + rsub) * (long)K + k0 + csub];
      __builtin_amdgcn_global_load_lds((gbl_ptr_t)sB, (lds_ptr_t)&Bs[rb * 64], 16, 0, 0);
    }
    __syncthreads();   // drains vmcnt -> tiles resident
#pragma unroll
    for (int kk = 0; kk < BK; kk += 32) {
      short8 af[4], bfr[4];
#pragma unroll
      for (int mt = 0; mt < 4; mt++)
        af[mt] = *(const short8*)&As[(wm + mt * 16 + l16) * 64 + kk + quad * 8];
#pragma unroll
      for (int nt = 0; nt < 4; nt++)
        bfr[nt] = *(const short8*)&Bs[(wn + nt * 16 + l16) * 64 + kk + quad * 8];
#pragma unroll
      for (int mt = 0; mt < 4; mt++)
#pragma unroll
        for (int nt = 0; nt < 4; nt++)
          acc[mt][nt] = __builtin_amdgcn_mfma_f32_16x16x32_bf16(af[mt], bfr[nt], acc[mt][nt], 0, 0, 0);
    }
    __syncthreads();
  }

#pragma unroll
  for (int mt = 0; mt < 4; mt++)
#pragma unroll
    for (int nt = 0; nt < 4; nt++)
#pragma unroll
      for (int r = 0; r < 4; r++) {
        long row = row0 + wm + mt * 16 + quad * 4 + r;
        long col = col0 + wn + nt * 16 + l16;
        float v = acc[mt][nt][r] + bias[col];
        if (MODE == 0) {
          int which = (int)(col >> 10);
          int hc = (int)col & 1023;
          int h = hc >> 6, d = hc & 63;
          int b = (int)(row >> 11), t = (int)row & 2047;
          ((unsigned short*)Cout)[(long)which * PLANE +
                                  (((long)(b * Hc + h) * Tc + t) << 6) + d] = f2bf(v);
        } else {
          ((float*)Cout)[row * N + col] = v;
        }
      }
}

// ---------- flash attention v6 ----------
// Round-3 staging (V^T b16 scatter, PD=72, grid (16,64)) + S^T operand swap +
// P KEPT IN REGISTERS: mfma_f32_16x16x16bf16_1k's A-layout (m=l16, k=quad*4+j)
// equals S^T's C-layout (q=l16, key=quad*4+r), so PV consumes sacc directly.
// No Ps buffer (LDS 18432 B), no P write->read serialization per tile.
__global__ __launch_bounds__(256) void flash_attn(const unsigned short* __restrict__ qkv,
                                                  unsigned short* __restrict__ attn_out) {
  constexpr int PD = 72;
  __shared__ __align__(16) short Ks[64 * PD];
  __shared__ __align__(16) short Vts[64 * PD];    // transposed: [d][key]
#if !HAVE_MFMA16
  __shared__ __align__(16) short Ps[4 * 16 * PD]; // fallback: per-wave P^T
#endif

  const int tid = threadIdx.x;
  const int wave = tid >> 6;
  const int lane = tid & 63;
  const int l16 = lane & 15;
  const int quad = lane >> 4;

  const int bh = blockIdx.y;          // b*16 + h
  const long base = (long)bh * Tc * DHc;
  const unsigned short* Qg = qkv + base;
  const unsigned short* Kg = qkv + PLANE + base;
  const unsigned short* Vg = qkv + 2 * PLANE + base;
  const int b = bh >> 4, h = bh & 15;

  constexpr float CEXP = 0.125f * 1.44269504f;  // 1/sqrt(64) folded into exp2
#if !HAVE_MFMA16
  short* Pw = &Ps[wave * 16 * PD];
#endif

  const int kr = tid >> 3;            // 0..31
  const int kc = (tid & 7) * 8;

#pragma unroll 1
  for (int pass = 0; pass < 2; pass++) {
    const int qx = (pass == 0) ? (int)blockIdx.x : (31 - (int)blockIdx.x);
    const int q0 = qx * 64 + wave * 16;  // wave's first q row

    // Q fragment (B-operand for S^T; A/B frags share the same per-lane layout)
    short8 qf[2];
#pragma unroll
    for (int kk = 0; kk < 2; kk++)
      qf[kk] = *(const short8*)&Qg[(long)(q0 + l16) * 64 + kk * 32 + quad * 8];

    floatx4 oacc[4];
#pragma unroll
    for (int j = 0; j < 4; j++) oacc[j] = (floatx4){0.f, 0.f, 0.f, 0.f};
    float lp = 0.f;  // row-sum partial for q = q0 + l16

    const int ntiles = qx + 1;

    // prologue: prefetch tile 0 into regs
    uint4 Kreg[2], Vreg[2];
    Kreg[0] = *(const uint4*)&Kg[(long)kr * 64 + kc];
    Kreg[1] = *(const uint4*)&Kg[(long)(32 + kr) * 64 + kc];
    Vreg[0] = *(const uint4*)&Vg[(long)lane * 64 + wave * 8];
    Vreg[1] = *(const uint4*)&Vg[(long)lane * 64 + (wave + 4) * 8];

#pragma unroll 1
    for (int kt = 0; kt < ntiles; kt++) {
      __syncthreads();  // all waves done reading LDS from previous tile
      // commit K (coalesced b128)
      *(uint4*)&Ks[kr * PD + kc] = Kreg[0];
      *(uint4*)&Ks[(32 + kr) * PD + kc] = Kreg[1];
      // commit V transposed (round-3 verified scatter; 2-way b16 = cheap)
#pragma unroll
      for (int c = 0; c < 2; c++) {
        int dc = wave + 4 * c;
        unsigned short vb[8];
        *(uint4*)vb = Vreg[c];
#pragma unroll
        for (int j = 0; j < 8; j++) Vts[(dc * 8 + j) * PD + lane] = (short)vb[j];
      }
      __syncthreads();  // staging visible
      // prefetch next tile (latency hidden behind compute)
      if (kt + 1 < ntiles) {
        long koff = (long)(kt + 1) * 64;
        Kreg[0] = *(const uint4*)&Kg[(koff + kr) * 64 + kc];
        Kreg[1] = *(const uint4*)&Kg[(koff + 32 + kr) * 64 + kc];
        Vreg[0] = *(const uint4*)&Vg[(koff + lane) * 64 + wave * 8];
        Vreg[1] = *(const uint4*)&Vg[(koff + lane) * 64 + (wave + 4) * 8];
      }

      // S^T[key][q]: sacc[nt] = keys nt*16+quad*4+r, q = q0+l16
      floatx4 sacc[4];
#pragma unroll
      for (int j = 0; j < 4; j++) sacc[j] = (floatx4){0.f, 0.f, 0.f, 0.f};
#pragma unroll
      for (int kk = 0; kk < 2; kk++) {
        short8 kf[4];
#pragma unroll
        for (int nt = 0; nt < 4; nt++)
          kf[nt] = *(const short8*)&Ks[(nt * 16 + l16) * PD + kk * 32 + quad * 8];
#pragma unroll
        for (int nt = 0; nt < 4; nt++)
          sacc[nt] = __builtin_amdgcn_mfma_f32_16x16x32_bf16(kf[nt], qf[kk], sacc[nt], 0, 0, 0);
      }

      // causal mask on diagonal tile: key = kt*64+nt*16+quad*4+r, q = q0+l16
      if (kt == qx) {
        int qi = q0 + l16;
#pragma unroll
        for (int nt = 0; nt < 4; nt++) {
          int kbase = kt * 64 + nt * 16 + quad * 4;
#pragma unroll
          for (int r = 0; r < 4; r++)
            if (kbase + r > qi) sacc[nt][r] = -3.0e38f;
        }
      }

      // p = exp(s/8); per-lane row-sum partial
#pragma unroll
      for (int nt = 0; nt < 4; nt++)
#pragma unroll
        for (int r = 0; r < 4; r++) sacc[nt][r] = exp2f(sacc[nt][r] * CEXP);
#pragma unroll
      for (int nt = 0; nt < 4; nt++)
        lp += (sacc[nt][0] + sacc[nt][1]) + (sacc[nt][2] + sacc[nt][3]);

#if HAVE_MFMA16
      // O += P @ V with K=16 steps: A-frag == sacc layout, zero data movement.
      // vf: B[k=s*16+quad*4+j][d=dt*16+l16] = Vts[(dt*16+l16)*PD + s*16+quad*4]
#pragma unroll
      for (int s = 0; s < 4; s++) {
        unsigned p01 = (unsigned)f2bf(sacc[s][0]) | ((unsigned)f2bf(sacc[s][1]) << 16);
        unsigned p23 = (unsigned)f2bf(sacc[s][2]) | ((unsigned)f2bf(sacc[s][3]) << 16);
        union { unsigned u[2]; short4_t v; } pf;
        pf.u[0] = p01; pf.u[1] = p23;
        short4_t vf[4];
#pragma unroll
        for (int dt = 0; dt < 4; dt++)
          vf[dt] = *(const short4_t*)&Vts[(dt * 16 + l16) * PD + s * 16 + quad * 4];
#pragma unroll
        for (int dt = 0; dt < 4; dt++)
          oacc[dt] = __builtin_amdgcn_mfma_f32_16x16x16bf16_1k(pf.v, vf[dt], oacc[dt], 0, 0, 0);
      }
#else
      // fallback: P^T via wave-private LDS, PV with 16x16x32
#pragma unroll
      for (int nt = 0; nt < 4; nt++) {
        unsigned u0 = (unsigned)f2bf(sacc[nt][0]) | ((unsigned)f2bf(sacc[nt][1]) << 16);
        unsigned u1 = (unsigned)f2bf(sacc[nt][2]) | ((unsigned)f2bf(sacc[nt][3]) << 16);
        uint2 u = {u0, u1};
        *(uint2*)&Pw[l16 * PD + nt * 16 + quad * 4] = u;
      }
#pragma unroll
      for (int kk = 0; kk < 2; kk++) {
        short8 pf = *(const short8*)&Pw[l16 * PD + kk * 32 + quad * 8];
        short8 vf[4];
#pragma unroll
        for (int dt = 0; dt < 4; dt++)
          vf[dt] = *(const short8*)&Vts[(dt * 16 + l16) * PD + kk * 32 + quad * 8];
#pragma unroll
        for (int dt = 0; dt < 4; dt++)
          oacc[dt] = __builtin_amdgcn_mfma_f32_16x16x32_bf16(pf, vf[dt], oacc[dt], 0, 0, 0);
      }
#endif
    }

    // epilogue: reduce l across quads (row q = l16), redistribute to C-rows
    float lv = lp + __shfl_xor(lp, 16);
    lv += __shfl_xor(lv, 32);             // all lanes: full row-sum for q = l16
#pragma unroll
    for (int r = 0; r < 4; r++) {
      float lr = __shfl(lv, quad * 4 + r); // l for this lane's C-row q = quad*4+r
      float inv = 1.0f / lr;
      int t = q0 + quad * 4 + r;
#pragma unroll
      for (int dt = 0; dt < 4; dt++) {
        int d = dt * 16 + l16;
        attn_out[(((long)(b * Tc + t) * Hc + h) << 6) + d] = f2bf(oacc[dt][r] * inv);
      }
    }
  }
}

// ---------- launch ----------
extern "C" void kernel_launch(void* const* d_in, const int* in_sizes, int n_in,
                              void* d_out, int out_size, void* d_ws, size_t ws_size,
                              hipStream_t stream) {
  const float* x = (const float*)d_in[0];
  const float* Wqkv = (const float*)d_in[1];
  const float* bqkv = (const float*)d_in[2];
  const float* Wout = (const float*)d_in[3];
  const float* bout = (const float*)d_in[4];

  char* ws = (char*)d_ws;
  unsigned short* x_bf   = (unsigned short*)ws;                       // 16 MB
  unsigned short* wqkv_t = (unsigned short*)(ws + 16777216);          // 6 MB
  unsigned short* wout_t = (unsigned short*)(ws + 16777216 + 6291456);// 2 MB
  unsigned short* qkv    = (unsigned short*)(ws + 25165824);          // 48 MB
  unsigned short* attn   = x_bf;  // reuse: x_bf dead after GEMM1

  // 1. casts / transposes
  cast_f32_bf16<<<dim3(Mrows * Dc / 4 / 256), dim3(256), 0, stream>>>(x, x_bf, Mrows * Dc / 4);
  transpose_cast<<<dim3(3 * Dc / 32, Dc / 32), dim3(256), 0, stream>>>(Wqkv, wqkv_t, Dc, 3 * Dc);
  transpose_cast<<<dim3(Dc / 32, Dc / 32), dim3(256), 0, stream>>>(Wout, wout_t, Dc, Dc);

  // 2. QKV projection
  gemm_bt<0><<<dim3(3 * Dc / 128, Mrows / 128), dim3(256), 0, stream>>>(
      x_bf, wqkv_t, bqkv, qkv, Mrows, 3 * Dc, Dc);

  // 3. flash attention (paired q-tiles, uniform 33 key-tiles per block)
  flash_attn<<<dim3(16, Bc * Hc), dim3(256), 0, stream>>>(qkv, attn);

  // 4. output projection (fp32 out + bias)
  gemm_bt<1><<<dim3(Dc / 128, Mrows / 128), dim3(256), 0, stream>>>(
      attn, wout_t, bout, d_out, Mrows, Dc, Dc);
}